// Round 2
// baseline (370.520 us; speedup 1.0000x reference)
//
#include <hip/hip_runtime.h>
#include <hip/hip_bf16.h>

// ScaledDotProdAttn (no softmax): attn = (q@k^T)/8 ; out = attn@v
// B=32, SQ=SK=2048, D=64, fp32 in/out. d_out = [out (32*2048*64)] ++ [attn (32*2048*2048)]
// R1: raw s_barrier (lgkmcnt-only) so attn stores / K,V loads stay in flight
//     across tiles (T4); register prefetch of next K/V tile (T14 issue-early/
//     write-late); V^T staging packed b32; attn stores reordered contiguous.

typedef __attribute__((ext_vector_type(4))) float  f32x4;
typedef __attribute__((ext_vector_type(8))) short  s16x8;

#define NB    32
#define SQL   2048
#define SKL   2048
#define DD    64
#define QBLK  128
#define KBLK  128
#define NTILES (SKL / KBLK)

// LDS layout (64 KB -> 2 blocks/CU):
//   [0      ,16384) K tile   : 128 rows(key) x 64 bf16, stride 128 B, sw128
//   [16384  ,32768) V^T tile : 64 rows(d)   x 128 bf16, stride 256 B, sw256
//   [32768  ,65536) S tile   : 128 rows(q)  x 128 bf16, stride 256 B, sw256
#define KS_OFF 0
#define VT_OFF 16384
#define SS_OFF 32768

__device__ __forceinline__ unsigned short f2bf(float f) {
    union { float f; unsigned u; } x; x.f = f;
    unsigned r = x.u + 0x7FFFu + ((x.u >> 16) & 1u);   // RNE
    return (unsigned short)(r >> 16);
}

// XOR swizzles: touch byte-addr bits 4..6 only (16B-aligned stays aligned).
__device__ __forceinline__ unsigned sw128(unsigned row, unsigned bc) {
    return row * 128u + (bc ^ ((row & 7u) << 4));
}
__device__ __forceinline__ unsigned sw256(unsigned row, unsigned bc) {
    return row * 256u + (bc ^ ((((row >> 3) ^ row) & 7u) << 4));
}

// Raw workgroup barrier: drain LDS ops only; global loads/stores stay in
// flight (the compiler still inserts vmcnt before any register USE of a
// load). asm "memory" clobbers pin IR-level motion on both sides;
// sched_barrier(0) pins the machine scheduler (rule #18).
__device__ __forceinline__ void bar_lds() {
    __builtin_amdgcn_sched_barrier(0);
    asm volatile("s_waitcnt lgkmcnt(0)" ::: "memory");
    __builtin_amdgcn_s_barrier();
    asm volatile("" ::: "memory");
    __builtin_amdgcn_sched_barrier(0);
}

__global__ __launch_bounds__(256, 2)
void sdpa_fused(const float* __restrict__ qg, const float* __restrict__ kg,
                const float* __restrict__ vg, float* __restrict__ og,
                float* __restrict__ ag) {
    __shared__ __align__(16) char smem[65536];

    const unsigned tid  = threadIdx.x;
    const unsigned wid  = tid >> 6;
    const unsigned lane = tid & 63u;
    const unsigned l15  = lane & 15u;
    const unsigned l4   = lane >> 4;        // 0..3
    const unsigned b    = blockIdx.x >> 4;
    const unsigned qt   = blockIdx.x & 15u;
    const unsigned qbase = qt * QBLK;
    const unsigned wr = wid >> 1, wc = wid & 1u;   // 2x2 wave grid for S

    const unsigned r0  = tid >> 3, c8 = tid & 7u;   // K staging map
    const unsigned t16 = tid >> 4, c4 = tid & 15u;  // V staging map

    // ---- stage Q (prescaled by 1/8) into SS region, sw128 layout ----
    {
        const float* src = qg + (size_t)b * SQL * DD + (size_t)qbase * DD;
        #pragma unroll
        for (int p = 0; p < 4; ++p) {
            unsigned row = p * 32 + r0;
            const f32x4* s = (const f32x4*)(src + row * DD + c8 * 8);
            f32x4 f0 = s[0], f1 = s[1];
            s16x8 h;
            #pragma unroll
            for (int j = 0; j < 4; ++j) {
                h[j]     = (short)f2bf(f0[j] * 0.125f);
                h[j + 4] = (short)f2bf(f1[j] * 0.125f);
            }
            *(s16x8*)(smem + SS_OFF + sw128(row, c8 * 16)) = h;
        }
    }
    bar_lds();

    // Q fragments are loop-invariant: hold in registers for the whole kernel.
    // (reads drain at the next bar_lds -> safe vs tile-0 S overwrite)
    s16x8 aq[4][2];
    #pragma unroll
    for (int m = 0; m < 4; ++m)
        #pragma unroll
        for (int ks = 0; ks < 2; ++ks)
            aq[m][ks] = *(const s16x8*)(smem + SS_OFF +
                        sw128(wr * 64 + m * 16 + l15, ks * 64 + l4 * 16));

    f32x4 acc_o[2][4];
    #pragma unroll
    for (int m = 0; m < 2; ++m)
        #pragma unroll
        for (int n = 0; n < 4; ++n)
            acc_o[m][n] = (f32x4){0.f, 0.f, 0.f, 0.f};

    const float* kbat = kg + (size_t)b * SKL * DD;
    const float* vbat = vg + (size_t)b * SKL * DD;

    // register prefetch buffers (fp32, converted at STAGE time so the vmcnt
    // wait lands one full tile after issue)
    f32x4 kbuf[4][2], vbuf[4][2];

    auto LOADT = [&](int kt) {
        const float* ksrc = kbat + (size_t)kt * KBLK * DD;
        const float* vsrc = vbat + (size_t)kt * KBLK * DD;
        #pragma unroll
        for (int p = 0; p < 4; ++p) {
            unsigned krow = p * 32 + r0;
            const f32x4* s = (const f32x4*)(ksrc + krow * DD + c8 * 8);
            kbuf[p][0] = s[0];
            kbuf[p][1] = s[1];
            unsigned vrow = p * 32 + 2 * t16;
            vbuf[p][0] = *(const f32x4*)(vsrc + vrow * DD + c4 * 4);
            vbuf[p][1] = *(const f32x4*)(vsrc + (vrow + 1) * DD + c4 * 4);
        }
    };

    auto STAGE = [&]() {
        #pragma unroll
        for (int p = 0; p < 4; ++p) {
            unsigned krow = p * 32 + r0;
            f32x4 f0 = kbuf[p][0], f1 = kbuf[p][1];
            s16x8 h;
            #pragma unroll
            for (int j = 0; j < 4; ++j) {
                h[j]     = (short)f2bf(f0[j]);
                h[j + 4] = (short)f2bf(f1[j]);
            }
            *(s16x8*)(smem + KS_OFF + sw128(krow, c8 * 16)) = h;

            unsigned vrow = p * 32 + 2 * t16;
            f32x4 g0 = vbuf[p][0], g1 = vbuf[p][1];
            #pragma unroll
            for (int j = 0; j < 4; ++j) {
                unsigned d = c4 * 4 + (unsigned)j;
                unsigned pack = (unsigned)f2bf(g0[j]) | ((unsigned)f2bf(g1[j]) << 16);
                *(unsigned*)(smem + VT_OFF + sw256(d, vrow * 2)) = pack;
            }
        }
    };

    LOADT(0);

    for (int kt = 0; kt < NTILES; ++kt) {
        STAGE();                          // consumes kbuf/vbuf (vmcnt waits here)
        if (kt + 1 < NTILES) LOADT(kt + 1);   // in flight across S + PV phases
        bar_lds();

        // ---- S = Q * K^T (scale folded into Q) ----
        f32x4 acc[4][4];
        #pragma unroll
        for (int m = 0; m < 4; ++m)
            #pragma unroll
            for (int n = 0; n < 4; ++n)
                acc[m][n] = (f32x4){0.f, 0.f, 0.f, 0.f};

        #pragma unroll
        for (int ks = 0; ks < 2; ++ks) {
            s16x8 bk[4];
            #pragma unroll
            for (int n = 0; n < 4; ++n)
                bk[n] = *(const s16x8*)(smem + KS_OFF +
                        sw128(wc * 64 + n * 16 + l15, ks * 64 + l4 * 16));
            #pragma unroll
            for (int m = 0; m < 4; ++m)
                #pragma unroll
                for (int n = 0; n < 4; ++n)
                    acc[m][n] = __builtin_amdgcn_mfma_f32_16x16x32_bf16(
                                    aq[m][ks], bk[n], acc[m][n], 0, 0, 0);
        }

        // ---- S->bf16 into LDS first, then attn fp32 stores (contiguous) ----
        #pragma unroll
        for (int m = 0; m < 4; ++m)
            #pragma unroll
            for (int n = 0; n < 4; ++n)
                #pragma unroll
                for (int i = 0; i < 4; ++i) {
                    unsigned ql = wr * 64 + m * 16 + l4 * 4 + (unsigned)i;
                    unsigned kl = wc * 64 + n * 16 + l15;
                    *(unsigned short*)(smem + SS_OFF + sw256(ql, kl * 2)) =
                        f2bf(acc[m][n][i]);
                }

        float* ap = ag + (size_t)b * SQL * SKL
                       + (size_t)(qbase + wr * 64 + l4 * 4) * SKL
                       + (size_t)kt * KBLK + wc * 64 + l15;
        #pragma unroll
        for (int m = 0; m < 4; ++m)
            #pragma unroll
            for (int i = 0; i < 4; ++i) {
                float* rowp = ap + (size_t)(m * 16 + i) * SKL;
                #pragma unroll
                for (int n = 0; n < 4; ++n)
                    __builtin_nontemporal_store(acc[m][n][i], rowp + n * 16);
            }
        bar_lds();

        // ---- O += S * V ---- (each wave: 32 q-rows x 64 d)
        #pragma unroll
        for (int ks = 0; ks < 4; ++ks) {
            s16x8 sa0 = *(const s16x8*)(smem + SS_OFF +
                        sw256(wid * 32 + l15,      ks * 64 + l4 * 16));
            s16x8 sa1 = *(const s16x8*)(smem + SS_OFF +
                        sw256(wid * 32 + 16 + l15, ks * 64 + l4 * 16));
            #pragma unroll
            for (int n = 0; n < 4; ++n) {
                s16x8 vb = *(const s16x8*)(smem + VT_OFF +
                           sw256(n * 16 + l15, ks * 64 + l4 * 16));
                acc_o[0][n] = __builtin_amdgcn_mfma_f32_16x16x32_bf16(sa0, vb, acc_o[0][n], 0, 0, 0);
                acc_o[1][n] = __builtin_amdgcn_mfma_f32_16x16x32_bf16(sa1, vb, acc_o[1][n], 0, 0, 0);
            }
        }
        bar_lds();
    }

    // ---- write O ----
    float* op = og + (size_t)b * SQL * DD
                   + (size_t)(qbase + wid * 32 + l4 * 4) * DD + l15;
    #pragma unroll
    for (int m = 0; m < 2; ++m)
        #pragma unroll
        for (int n = 0; n < 4; ++n)
            #pragma unroll
            for (int i = 0; i < 4; ++i)
                __builtin_nontemporal_store(acc_o[m][n][i], op + (m * 16 + i) * DD + n * 16);
}

extern "C" void kernel_launch(void* const* d_in, const int* in_sizes, int n_in,
                              void* d_out, int out_size, void* d_ws, size_t ws_size,
                              hipStream_t stream) {
    const float* q = (const float*)d_in[0];
    const float* k = (const float*)d_in[1];
    const float* v = (const float*)d_in[2];
    float* outp  = (float*)d_out;                      // [32][2048][64]
    float* attnp = outp + (size_t)NB * SQL * DD;       // [32][2048][2048]
    sdpa_fused<<<dim3(NB * (SQL / QBLK)), dim3(256), 0, stream>>>(q, k, v, outp, attnp);
}